// Round 9
// baseline (384.539 us; speedup 1.0000x reference)
//
#include <hip/hip_runtime.h>
#include <hip/hip_bf16.h>
#include <math.h>

#define NV 100000
#define NE_N 100000
#define NEDGE 250000
#define NEG 0.2f
#define LN_EPS 1e-5f

typedef __bf16 bf16_t;
typedef __bf16 bf16x8 __attribute__((ext_vector_type(8)));
typedef float f32x4 __attribute__((ext_vector_type(4)));

__device__ inline unsigned short f2bfu(float f) {
    return __builtin_bit_cast(unsigned short, (__bf16)f);
}
__device__ inline float bfu2f(unsigned short u) {
    return (float)__builtin_bit_cast(__bf16, u);
}
__device__ inline float blo(unsigned w) { return __uint_as_float(w << 16); }
__device__ inline float bhi(unsigned w) { return __uint_as_float(w & 0xffff0000u); }
__device__ inline float lrelu(float x) { return x > 0.f ? x : NEG * x; }
__device__ inline unsigned pk2(float a, float b) {
    return (unsigned)f2bfu(a) | ((unsigned)f2bfu(b) << 16);
}

// ---------------------------------------------------------------------------
// prep: pack W matrices into bf16 A-fragment order:
//   pack[((ksq)*N + col)*8 + j] = W[ksq*8 + j][col],  ksq = 0..15 (K=128)
// ---------------------------------------------------------------------------
__global__ __launch_bounds__(256) void prep_kernel(
    const float* __restrict__ Wsrc, const float* __restrict__ Wdst,
    const float* __restrict__ Wp, bf16_t* __restrict__ pS,
    bf16_t* __restrict__ pD, bf16_t* __restrict__ pP)
{
    int t = blockIdx.x * 256 + threadIdx.x;
    if (t < 8192) {
        int ksq = t >> 9, col = t & 511;
#pragma unroll
        for (int j = 0; j < 8; ++j)
            pS[(size_t)t * 8 + j] = (bf16_t)Wsrc[(ksq * 8 + j) * 512 + col];
    } else if (t < 16384) {
        int g = t - 8192;
        int ksq = g >> 9, col = g & 511;
#pragma unroll
        for (int j = 0; j < 8; ++j)
            pD[(size_t)g * 8 + j] = (bf16_t)Wdst[(ksq * 8 + j) * 512 + col];
    } else if (t < 18432) {
        int g = t - 16384;
        int ksq = g >> 7, col = g & 127;
#pragma unroll
        for (int j = 0; j < 8; ++j)
            pP[(size_t)g * 8 + j] = (bf16_t)Wp[(ksq * 8 + j) * 128 + col];
    }
}

// ---------------------------------------------------------------------------
// CSR build kernels
// ---------------------------------------------------------------------------
__global__ __launch_bounds__(256) void count_kernel(
    const int* __restrict__ dst, int* __restrict__ deg)
{
    int t = blockIdx.x * 256 + threadIdx.x;
    if (t < NEDGE) atomicAdd(&deg[dst[t]], 1);
}

__global__ __launch_bounds__(256) void scan1_kernel(
    const int* __restrict__ deg, int* __restrict__ offs, int* __restrict__ bsum)
{
    __shared__ int s[256];
    int i = blockIdx.x * 256 + threadIdx.x;
    int v = (i < NE_N) ? deg[i] : 0;
    s[threadIdx.x] = v;
    __syncthreads();
    for (int off = 1; off < 256; off <<= 1) {
        int t_ = (threadIdx.x >= off) ? s[threadIdx.x - off] : 0;
        __syncthreads();
        s[threadIdx.x] += t_;
        __syncthreads();
    }
    if (i < NE_N) offs[i] = s[threadIdx.x] - v;   // exclusive within block
    if (threadIdx.x == 255) bsum[blockIdx.x] = s[255];
}

__global__ __launch_bounds__(512) void scan2_kernel(int* __restrict__ bsum, int nb)
{
    __shared__ int s[512];
    int t = threadIdx.x;
    int v = (t < nb) ? bsum[t] : 0;
    s[t] = v;
    __syncthreads();
    for (int off = 1; off < 512; off <<= 1) {
        int t_ = (t >= off) ? s[t - off] : 0;
        __syncthreads();
        s[t] += t_;
        __syncthreads();
    }
    if (t < nb) bsum[t] = s[t] - v;               // exclusive
}

__global__ __launch_bounds__(256) void scan3_kernel(
    int* __restrict__ offs, const int* __restrict__ bsum, int* __restrict__ cursor)
{
    int i = blockIdx.x * 256 + threadIdx.x;
    if (i < NE_N) {
        int o = offs[i] + bsum[blockIdx.x];
        offs[i] = o;
        cursor[i] = o;
    }
}

__global__ __launch_bounds__(256) void scatter_kernel(
    const int* __restrict__ dst, int* __restrict__ cursor, int* __restrict__ eidx)
{
    int t = blockIdx.x * 256 + threadIdx.x;
    if (t < NEDGE) {
        int pos = atomicAdd(&cursor[dst[t]], 1);
        eidx[pos] = t;
    }
}

// ---------------------------------------------------------------------------
// Fused encoder + MFMA projection — fully WAVE-LOCAL, zero __syncthreads().
// Wave w owns rows w*16..w*16+15 end-to-end:
//   encoder: lane owns cols 2l,2l+1 of those 16 rows -> bf16 pair to Hs
//   LN stats: 4x ds_read_b128/lane over own rows, quad shuffle-reduce,
//             mu/inv kept in registers
//   B-frags: unpack own rows, apply LN affine in-register
//   MFMA over 512 cols; staging reuses own Hs rows for 64B-line stores
// ---------------------------------------------------------------------------
__global__ __launch_bounds__(256, 6) void enc_proj_kernel(
    const float* __restrict__ feat,
    const float* __restrict__ Wenc, const float* __restrict__ benc,
    const float* __restrict__ gln, const float* __restrict__ beta,
    const bf16_t* __restrict__ Apack, const float* __restrict__ bproj,
    unsigned short* __restrict__ out, int M)
{
    __shared__ unsigned short Hs[64 * 136];

    int t = threadIdx.x;
    int l = t & 63;
    int w = t >> 6;
    int row0 = blockIdx.x * 64;
    int rbase = w * 16;                       // wave's first local row

    // ---- encoder: lane owns cols 2l, 2l+1 for the wave's 16 rows
    float wc0[16], wc1[16];
#pragma unroll
    for (int k = 0; k < 16; ++k) {
        float2 wv = *(const float2*)(Wenc + k * 128 + 2 * l);
        wc0[k] = wv.x;
        wc1[k] = wv.y;
    }
    float2 bv2 = *(const float2*)(benc + 2 * l);

#pragma unroll
    for (int i = 0; i < 16; ++i) {
        int grow = row0 + rbase + i;
        if (grow >= M) grow = M - 1;          // wave-uniform clamp
        const float* fr = feat + (size_t)grow * 16;
        float a0 = bv2.x, a1 = bv2.y;
#pragma unroll
        for (int k = 0; k < 16; ++k) {
            float f = fr[k];
            a0 = fmaf(f, wc0[k], a0);
            a1 = fmaf(f, wc1[k], a1);
        }
        a0 = fmaxf(a0, 0.f);
        a1 = fmaxf(a1, 0.f);
        *(unsigned*)&Hs[(rbase + i) * 136 + 2 * l] = pk2(a0, a1);
    }

    // ---- LN stats, wave-local: lane -> (own row l>>2, quad l&3)
    float s = 0.f, s2 = 0.f;
    {
        int rr = rbase + (l >> 2);
        int q = l & 3;
#pragma unroll
        for (int j = 0; j < 4; ++j) {
            uint4 v = *(const uint4*)&Hs[rr * 136 + q * 32 + j * 8];
            float x;
            x = blo(v.x); s += x; s2 = fmaf(x, x, s2);
            x = bhi(v.x); s += x; s2 = fmaf(x, x, s2);
            x = blo(v.y); s += x; s2 = fmaf(x, x, s2);
            x = bhi(v.y); s += x; s2 = fmaf(x, x, s2);
            x = blo(v.z); s += x; s2 = fmaf(x, x, s2);
            x = bhi(v.z); s += x; s2 = fmaf(x, x, s2);
            x = blo(v.w); s += x; s2 = fmaf(x, x, s2);
            x = bhi(v.w); s += x; s2 = fmaf(x, x, s2);
        }
    }
    s  += __shfl_xor(s, 1, 64);  s  += __shfl_xor(s, 2, 64);
    s2 += __shfl_xor(s2, 1, 64); s2 += __shfl_xor(s2, 2, 64);
    float mu  = s * (1.f / 128.f);
    float var = s2 * (1.f / 128.f) - mu * mu;
    float inv = rsqrtf(var + LN_EPS);

    // ---- B-fragments with LN affine folded in (registers only)
    int kq = l >> 4;
    int ln = l & 15;
    float mu_r  = __shfl(mu,  ln * 4, 64);    // stats live at lane row*4
    float inv_r = __shfl(inv, ln * 4, 64);

    bf16x8 bfr[4];
#pragma unroll
    for (int ks = 0; ks < 4; ++ks) {
        int c0 = ks * 32 + kq * 8;
        uint4 v = *(const uint4*)&Hs[(rbase + ln) * 136 + c0];
        float4 g0 = *(const float4*)(gln + c0);
        float4 g1 = *(const float4*)(gln + c0 + 4);
        float4 b0 = *(const float4*)(beta + c0);
        float4 b1 = *(const float4*)(beta + c0 + 4);
        uint4 p;
        p.x = pk2(fmaf((blo(v.x) - mu_r) * inv_r, g0.x, b0.x),
                  fmaf((bhi(v.x) - mu_r) * inv_r, g0.y, b0.y));
        p.y = pk2(fmaf((blo(v.y) - mu_r) * inv_r, g0.z, b0.z),
                  fmaf((bhi(v.y) - mu_r) * inv_r, g0.w, b0.w));
        p.z = pk2(fmaf((blo(v.z) - mu_r) * inv_r, g1.x, b1.x),
                  fmaf((bhi(v.z) - mu_r) * inv_r, g1.y, b1.y));
        p.w = pk2(fmaf((blo(v.w) - mu_r) * inv_r, g1.z, b1.z),
                  fmaf((bhi(v.w) - mu_r) * inv_r, g1.w, b1.w));
        bfr[ks] = __builtin_bit_cast(bf16x8, p);
    }

    // ---- MFMA over 512 cols; wave-private staging in own Hs rows
    unsigned short* stag = Hs + rbase * 136;
    int node = row0 + rbase + ln;
    bool wr = node < M;

#pragma unroll
    for (int pass = 0; pass < 4; ++pass) {
        int colp = pass * 128;
#pragma unroll
        for (int mt = 0; mt < 8; ++mt) {
            int colA = colp + mt * 16 + ln;
            bf16x8 afr[4];
#pragma unroll
            for (int ks = 0; ks < 4; ++ks)
                afr[ks] = *(const bf16x8*)(Apack + ((size_t)(ks * 4 + kq) * 512 + colA) * 8);

            f32x4 acc = {0.f, 0.f, 0.f, 0.f};
#pragma unroll
            for (int ks = 0; ks < 4; ++ks)
                acc = __builtin_amdgcn_mfma_f32_16x16x32_bf16(afr[ks], bfr[ks], acc, 0, 0, 0);

            int col = colp + mt * 16 + kq * 4;
            float4 bb = *(const float4*)(bproj + col);
            ushort4 o;
            o.x = f2bfu(acc[0] + bb.x);
            o.y = f2bfu(acc[1] + bb.y);
            o.z = f2bfu(acc[2] + bb.z);
            o.w = f2bfu(acc[3] + bb.w);
            *(ushort4*)&stag[ln * 136 + mt * 16 + kq * 4] = o;
        }
        // 16 rows x 128 cols -> full 64B-line stores
#pragma unroll
        for (int i = 0; i < 4; ++i) {
            uint4 v = *(const uint4*)&stag[ln * 136 + i * 32 + kq * 8];
            if (wr)
                *(uint4*)(out + (size_t)node * 512 + colp + i * 32 + kq * 8) = v;
        }
    }
}

// ---------------------------------------------------------------------------
// final GEMM (MFMA): C[M,128] = relu(A[M,128] @ Wp + bp), in place (A == C)
// ---------------------------------------------------------------------------
__global__ __launch_bounds__(256) void final_gemm_kernel(
    const float* __restrict__ A, const bf16_t* __restrict__ Ppack,
    const float* __restrict__ bp, float* __restrict__ C, int M)
{
    __shared__ unsigned short Hs[64 * 136];
    int t = threadIdx.x;
    int lane = t & 63;
    int w = t >> 6;
    int row0 = blockIdx.x * 64;

#pragma unroll
    for (int i = 0; i < 8; ++i) {
        int f4 = i * 256 + t;
        int r = f4 >> 5;
        int c4 = (f4 & 31) * 4;
        float4 v = make_float4(0.f, 0.f, 0.f, 0.f);
        if (row0 + r < M)
            v = ((const float4*)(A + (size_t)(row0 + r) * 128))[f4 & 31];
        ushort4 o;
        o.x = f2bfu(v.x); o.y = f2bfu(v.y); o.z = f2bfu(v.z); o.w = f2bfu(v.w);
        *(ushort4*)&Hs[r * 136 + c4] = o;
    }
    __syncthreads();

    int kq = lane >> 4;
    int ln = lane & 15;

    f32x4 acc[2][4];
#pragma unroll
    for (int mt = 0; mt < 2; ++mt)
#pragma unroll
        for (int nt = 0; nt < 4; ++nt) {
            f32x4 z = {0.f, 0.f, 0.f, 0.f};
            acc[mt][nt] = z;
        }

#pragma unroll
    for (int ks = 0; ks < 4; ++ks) {
        bf16x8 bfr[4];
#pragma unroll
        for (int nt = 0; nt < 4; ++nt) {
            const uint4* p = (const uint4*)&Hs[(nt * 16 + ln) * 136 + ks * 32 + kq * 8];
            bfr[nt] = __builtin_bit_cast(bf16x8, *p);
        }
        bf16x8 afr[2];
#pragma unroll
        for (int mt = 0; mt < 2; ++mt) {
            int colA = w * 32 + mt * 16 + ln;
            afr[mt] = *(const bf16x8*)(Ppack + ((size_t)(ks * 4 + kq) * 128 + colA) * 8);
        }
#pragma unroll
        for (int mt = 0; mt < 2; ++mt)
#pragma unroll
            for (int nt = 0; nt < 4; ++nt)
                acc[mt][nt] = __builtin_amdgcn_mfma_f32_16x16x32_bf16(
                    afr[mt], bfr[nt], acc[mt][nt], 0, 0, 0);
    }

#pragma unroll
    for (int mt = 0; mt < 2; ++mt) {
        int col = w * 32 + mt * 16 + kq * 4;
        float4 bb = *(const float4*)(bp + col);
#pragma unroll
        for (int nt = 0; nt < 4; ++nt) {
            int node = row0 + nt * 16 + ln;
            if (node < M) {
                float4 o;
                o.x = fmaxf(acc[mt][nt][0] + bb.x, 0.f);
                o.y = fmaxf(acc[mt][nt][1] + bb.y, 0.f);
                o.z = fmaxf(acc[mt][nt][2] + bb.z, 0.f);
                o.w = fmaxf(acc[mt][nt][3] + bb.w, 0.f);
                *(float4*)(C + (size_t)node * 128 + col) = o;
            }
        }
    }
}

// ---------------------------------------------------------------------------
// FUSED score + segment-softmax + aggregate (online softmax, no atomics).
// ---------------------------------------------------------------------------
__global__ __launch_bounds__(256) void softagg_kernel(
    const unsigned short* __restrict__ fs, const unsigned short* __restrict__ fdp,
    const float* __restrict__ attn, const int* __restrict__ src,
    const int* __restrict__ offs, const int* __restrict__ deg,
    const int* __restrict__ eidx, float* __restrict__ out)
{
    int d = blockIdx.x * 4 + (threadIdx.x >> 6);
    if (d >= NE_N) return;
    int l = threadIdx.x & 63;
    int r0 = offs[d];
    int n = deg[d];
    int o = l * 8;

    uint4 fv = *(const uint4*)(fdp + (size_t)d * 512 + o);
    float fdv[8] = { blo(fv.x), bhi(fv.x), blo(fv.y), bhi(fv.y),
                     blo(fv.z), bhi(fv.z), blo(fv.w), bhi(fv.w) };
    float4 w0 = *(const float4*)(attn + o);
    float4 w1 = *(const float4*)(attn + o + 4);
    float wv[8] = { w0.x, w0.y, w0.z, w0.w, w1.x, w1.y, w1.z, w1.w };

    float m = -1e30f, sm = 0.f;
    float acc[8];
#pragma unroll
    for (int j = 0; j < 8; ++j) acc[j] = 0.f;

    for (int base = 0; base < n; base += 64) {
        int cnt = min(n - base, 64);
        int sl = 0;
        if (l < cnt) sl = src[eidx[r0 + base + l]];
        for (int i = 0; i < cnt; ++i) {
            int s = __shfl(sl, i, 64);
            uint4 a = *(const uint4*)(fs + (size_t)s * 512 + o);
            float fsv[8] = { blo(a.x), bhi(a.x), blo(a.y), bhi(a.y),
                             blo(a.z), bhi(a.z), blo(a.w), bhi(a.w) };
            float p = 0.f;
#pragma unroll
            for (int j = 0; j < 8; ++j)
                p = fmaf(lrelu(fsv[j] + fdv[j]), wv[j], p);
#pragma unroll
            for (int mk = 1; mk < 16; mk <<= 1)
                p += __shfl_xor(p, mk, 64);
            float mn = fmaxf(m, p);
            float c  = __expf(m - mn);
            float av = __expf(p - mn);
            sm = sm * c + av;
            m = mn;
#pragma unroll
            for (int j = 0; j < 8; ++j)
                acc[j] = fmaf(av, fsv[j], acc[j] * c);
        }
    }

    float inv = (n > 0) ? 0.25f / sm : 0.f;
#pragma unroll
    for (int j = 0; j < 8; ++j) {
        float v = acc[j] * inv;
        v += __shfl_xor(v, 16, 64);
        v += __shfl_xor(v, 32, 64);
        acc[j] = v;
    }
    if (l < 16) {
        float4 o0 = make_float4(acc[0], acc[1], acc[2], acc[3]);
        float4 o1 = make_float4(acc[4], acc[5], acc[6], acc[7]);
        *(float4*)(out + (size_t)d * 128 + l * 8) = o0;
        *(float4*)(out + (size_t)d * 128 + l * 8 + 4) = o1;
    }
}

// ---------------------------------------------------------------------------
extern "C" void kernel_launch(void* const* d_in, const int* in_sizes, int n_in,
                              void* d_out, int out_size, void* d_ws, size_t ws_size,
                              hipStream_t stream)
{
    const float* v_feat = (const float*)d_in[0];
    const float* e_feat = (const float*)d_in[1];
    const float* Wv     = (const float*)d_in[2];
    const float* bv     = (const float*)d_in[3];
    const float* gv     = (const float*)d_in[4];
    const float* betav  = (const float*)d_in[5];
    const float* We     = (const float*)d_in[6];
    const float* be     = (const float*)d_in[7];
    const float* ge     = (const float*)d_in[8];
    const float* betae  = (const float*)d_in[9];
    const float* Wsrc   = (const float*)d_in[10];
    const float* bsrc   = (const float*)d_in[11];
    const float* Wdst   = (const float*)d_in[12];
    const float* bdst   = (const float*)d_in[13];
    const float* attn   = (const float*)d_in[14];
    const float* Wp     = (const float*)d_in[15];
    const float* bp     = (const float*)d_in[16];
    const int*   src    = (const int*)d_in[17];
    const int*   dst    = (const int*)d_in[18];
    float* out = (float*)d_out;

    unsigned short* fs = (unsigned short*)d_ws;
    unsigned short* fd = fs + (size_t)NV * 512;
    int* deg    = (int*)(fd + (size_t)NE_N * 512);
    int* offs   = deg + NE_N;
    int* cursor = offs + NE_N;
    int* bsum   = cursor + NE_N;
    int* eidx   = bsum + 512;
    bf16_t* pS  = (bf16_t*)(eidx + NEDGE);
    bf16_t* pD  = pS + 65536;
    bf16_t* pP  = pD + 65536;

    const int NB_SCAN = (NE_N + 255) / 256;   // 391

    prep_kernel<<<72, 256, 0, stream>>>(Wsrc, Wdst, Wp, pS, pD, pP);

    // CSR build
    hipMemsetAsync(deg, 0, (size_t)NE_N * sizeof(int), stream);
    count_kernel<<<(NEDGE + 255) / 256, 256, 0, stream>>>(dst, deg);
    scan1_kernel<<<NB_SCAN, 256, 0, stream>>>(deg, offs, bsum);
    scan2_kernel<<<1, 512, 0, stream>>>(bsum, NB_SCAN);
    scan3_kernel<<<NB_SCAN, 256, 0, stream>>>(offs, bsum, cursor);
    scatter_kernel<<<(NEDGE + 255) / 256, 256, 0, stream>>>(dst, cursor, eidx);

    enc_proj_kernel<<<1563, 256, 0, stream>>>(v_feat, Wv, bv, gv, betav,
                                              pS, bsrc, fs, NV);
    enc_proj_kernel<<<1563, 256, 0, stream>>>(e_feat, We, be, ge, betae,
                                              pD, bdst, fd, NE_N);

    softagg_kernel<<<NE_N / 4, 256, 0, stream>>>(fs, fd, attn, src, offs, deg,
                                                 eidx, out);

    final_gemm_kernel<<<1563, 256, 0, stream>>>(out, pP, bp, out, NE_N);
}

// Round 10
// 334.809 us; speedup vs baseline: 1.1485x; 1.1485x over previous
//
#include <hip/hip_runtime.h>
#include <hip/hip_bf16.h>
#include <math.h>

#define NV 100000
#define NE_N 100000
#define NEDGE 250000
#define NEG 0.2f
#define LN_EPS 1e-5f

typedef __bf16 bf16_t;
typedef __bf16 bf16x8 __attribute__((ext_vector_type(8)));
typedef float f32x4 __attribute__((ext_vector_type(4)));

__device__ inline unsigned short f2bfu(float f) {
    return __builtin_bit_cast(unsigned short, (__bf16)f);
}
__device__ inline float bfu2f(unsigned short u) {
    return (float)__builtin_bit_cast(__bf16, u);
}
__device__ inline float blo(unsigned w) { return __uint_as_float(w << 16); }
__device__ inline float bhi(unsigned w) { return __uint_as_float(w & 0xffff0000u); }
__device__ inline float lrelu(float x) { return x > 0.f ? x : NEG * x; }
__device__ inline unsigned pk2(float a, float b) {
    return (unsigned)f2bfu(a) | ((unsigned)f2bfu(b) << 16);
}

// ---------------------------------------------------------------------------
// prep: pack W matrices into bf16 A-fragment order:
//   pack[((ksq)*N + col)*8 + j] = W[ksq*8 + j][col],  ksq = 0..15 (K=128)
// ---------------------------------------------------------------------------
__global__ __launch_bounds__(256) void prep_kernel(
    const float* __restrict__ Wsrc, const float* __restrict__ Wdst,
    const float* __restrict__ Wp, bf16_t* __restrict__ pS,
    bf16_t* __restrict__ pD, bf16_t* __restrict__ pP)
{
    int t = blockIdx.x * 256 + threadIdx.x;
    if (t < 8192) {
        int ksq = t >> 9, col = t & 511;
#pragma unroll
        for (int j = 0; j < 8; ++j)
            pS[(size_t)t * 8 + j] = (bf16_t)Wsrc[(ksq * 8 + j) * 512 + col];
    } else if (t < 16384) {
        int g = t - 8192;
        int ksq = g >> 9, col = g & 511;
#pragma unroll
        for (int j = 0; j < 8; ++j)
            pD[(size_t)g * 8 + j] = (bf16_t)Wdst[(ksq * 8 + j) * 512 + col];
    } else if (t < 18432) {
        int g = t - 16384;
        int ksq = g >> 7, col = g & 127;
#pragma unroll
        for (int j = 0; j < 8; ++j)
            pP[(size_t)g * 8 + j] = (bf16_t)Wp[(ksq * 8 + j) * 128 + col];
    }
}

// ---------------------------------------------------------------------------
// CSR build kernels
// ---------------------------------------------------------------------------
__global__ __launch_bounds__(256) void count_kernel(
    const int* __restrict__ dst, int* __restrict__ deg)
{
    int t = blockIdx.x * 256 + threadIdx.x;
    if (t < NEDGE) atomicAdd(&deg[dst[t]], 1);
}

__global__ __launch_bounds__(256) void scan1_kernel(
    const int* __restrict__ deg, int* __restrict__ offs, int* __restrict__ bsum)
{
    __shared__ int s[256];
    int i = blockIdx.x * 256 + threadIdx.x;
    int v = (i < NE_N) ? deg[i] : 0;
    s[threadIdx.x] = v;
    __syncthreads();
    for (int off = 1; off < 256; off <<= 1) {
        int t_ = (threadIdx.x >= off) ? s[threadIdx.x - off] : 0;
        __syncthreads();
        s[threadIdx.x] += t_;
        __syncthreads();
    }
    if (i < NE_N) offs[i] = s[threadIdx.x] - v;   // exclusive within block
    if (threadIdx.x == 255) bsum[blockIdx.x] = s[255];
}

__global__ __launch_bounds__(512) void scan2_kernel(int* __restrict__ bsum, int nb)
{
    __shared__ int s[512];
    int t = threadIdx.x;
    int v = (t < nb) ? bsum[t] : 0;
    s[t] = v;
    __syncthreads();
    for (int off = 1; off < 512; off <<= 1) {
        int t_ = (t >= off) ? s[t - off] : 0;
        __syncthreads();
        s[t] += t_;
        __syncthreads();
    }
    if (t < nb) bsum[t] = s[t] - v;               // exclusive
}

__global__ __launch_bounds__(256) void scan3_kernel(
    int* __restrict__ offs, const int* __restrict__ bsum, int* __restrict__ cursor)
{
    int i = blockIdx.x * 256 + threadIdx.x;
    if (i < NE_N) {
        int o = offs[i] + bsum[blockIdx.x];
        offs[i] = o;
        cursor[i] = o;
    }
}

__global__ __launch_bounds__(256) void scatter_kernel(
    const int* __restrict__ dst, int* __restrict__ cursor, int* __restrict__ eidx)
{
    int t = blockIdx.x * 256 + threadIdx.x;
    if (t < NEDGE) {
        int pos = atomicAdd(&cursor[dst[t]], 1);
        eidx[pos] = t;
    }
}

// ---------------------------------------------------------------------------
// Fused encoder + MFMA projection — wave-local, zero __syncthreads(),
// BOTH node types in one launch (blockIdx selects v / e inputs).
// Key fixes vs r9: rbase scalarized (feat -> s_load), launch_bounds(256,4)
// for 128-VGPR budget, explicit 2-stage Apack prefetch pipeline.
// ---------------------------------------------------------------------------
__global__ __launch_bounds__(256, 4) void enc_proj_kernel(
    const float* __restrict__ featV, const float* __restrict__ WencV,
    const float* __restrict__ bencV, const float* __restrict__ gV,
    const float* __restrict__ betaV, const bf16_t* __restrict__ ApackV,
    const float* __restrict__ bprojV, unsigned short* __restrict__ outV,
    const float* __restrict__ featE, const float* __restrict__ WencE,
    const float* __restrict__ bencE, const float* __restrict__ gE,
    const float* __restrict__ betaE, const bf16_t* __restrict__ ApackE,
    const float* __restrict__ bprojE, unsigned short* __restrict__ outE,
    int nblk1, int M)
{
    __shared__ unsigned short Hs[64 * 136];

    int b = blockIdx.x;
    bool isV = b < nblk1;
    const float* feat  = isV ? featV  : featE;
    const float* Wenc  = isV ? WencV  : WencE;
    const float* benc  = isV ? bencV  : bencE;
    const float* gln   = isV ? gV     : gE;
    const float* beta  = isV ? betaV  : betaE;
    const bf16_t* Apack = isV ? ApackV : ApackE;
    const float* bproj = isV ? bprojV : bprojE;
    unsigned short* out = isV ? outV : outE;
    int row0 = (isV ? b : b - nblk1) * 64;

    int t = threadIdx.x;
    int l = t & 63;
    int w = t >> 6;
    int rbase = __builtin_amdgcn_readfirstlane(w * 16);  // scalar row base

    // ---- encoder: lane owns cols 2l, 2l+1 for the wave's 16 rows
    float wc0[16], wc1[16];
#pragma unroll
    for (int k = 0; k < 16; ++k) {
        float2 wv = *(const float2*)(Wenc + k * 128 + 2 * l);
        wc0[k] = wv.x;
        wc1[k] = wv.y;
    }
    float2 bv2 = *(const float2*)(benc + 2 * l);

#pragma unroll
    for (int i = 0; i < 16; ++i) {
        int grow = row0 + rbase + i;
        if (grow >= M) grow = M - 1;          // wave-uniform clamp
        const float* fr = feat + (size_t)grow * 16;
        float a0 = bv2.x, a1 = bv2.y;
#pragma unroll
        for (int k = 0; k < 16; ++k) {
            float f = fr[k];                  // scalar (wave-uniform) load
            a0 = fmaf(f, wc0[k], a0);
            a1 = fmaf(f, wc1[k], a1);
        }
        a0 = fmaxf(a0, 0.f);
        a1 = fmaxf(a1, 0.f);
        *(unsigned*)&Hs[(rbase + i) * 136 + 2 * l] = pk2(a0, a1);
    }

    // ---- LN stats, wave-local: lane -> (own row l>>2, quad l&3)
    float s = 0.f, s2 = 0.f;
    {
        int rr = rbase + (l >> 2);
        int q = l & 3;
#pragma unroll
        for (int j = 0; j < 4; ++j) {
            uint4 v = *(const uint4*)&Hs[rr * 136 + q * 32 + j * 8];
            float x;
            x = blo(v.x); s += x; s2 = fmaf(x, x, s2);
            x = bhi(v.x); s += x; s2 = fmaf(x, x, s2);
            x = blo(v.y); s += x; s2 = fmaf(x, x, s2);
            x = bhi(v.y); s += x; s2 = fmaf(x, x, s2);
            x = blo(v.z); s += x; s2 = fmaf(x, x, s2);
            x = bhi(v.z); s += x; s2 = fmaf(x, x, s2);
            x = blo(v.w); s += x; s2 = fmaf(x, x, s2);
            x = bhi(v.w); s += x; s2 = fmaf(x, x, s2);
        }
    }
    s  += __shfl_xor(s, 1, 64);  s  += __shfl_xor(s, 2, 64);
    s2 += __shfl_xor(s2, 1, 64); s2 += __shfl_xor(s2, 2, 64);
    float mu  = s * (1.f / 128.f);
    float var = s2 * (1.f / 128.f) - mu * mu;
    float inv = rsqrtf(var + LN_EPS);

    // ---- B-fragments with LN affine folded in (registers only)
    int kq = l >> 4;
    int ln = l & 15;
    float mu_r  = __shfl(mu,  ln * 4, 64);    // stats live at lane row*4
    float inv_r = __shfl(inv, ln * 4, 64);

    bf16x8 bfr[4];
#pragma unroll
    for (int ks = 0; ks < 4; ++ks) {
        int c0 = ks * 32 + kq * 8;
        uint4 v = *(const uint4*)&Hs[(rbase + ln) * 136 + c0];
        float4 g0 = *(const float4*)(gln + c0);
        float4 g1 = *(const float4*)(gln + c0 + 4);
        float4 b0 = *(const float4*)(beta + c0);
        float4 b1 = *(const float4*)(beta + c0 + 4);
        uint4 p;
        p.x = pk2(fmaf((blo(v.x) - mu_r) * inv_r, g0.x, b0.x),
                  fmaf((bhi(v.x) - mu_r) * inv_r, g0.y, b0.y));
        p.y = pk2(fmaf((blo(v.y) - mu_r) * inv_r, g0.z, b0.z),
                  fmaf((bhi(v.y) - mu_r) * inv_r, g0.w, b0.w));
        p.z = pk2(fmaf((blo(v.z) - mu_r) * inv_r, g1.x, b1.x),
                  fmaf((bhi(v.z) - mu_r) * inv_r, g1.y, b1.y));
        p.w = pk2(fmaf((blo(v.w) - mu_r) * inv_r, g1.z, b1.z),
                  fmaf((bhi(v.w) - mu_r) * inv_r, g1.w, b1.w));
        bfr[ks] = __builtin_bit_cast(bf16x8, p);
    }

    // ---- MFMA over 512 cols; 2-stage Apack prefetch pipeline;
    //      wave-private staging in own Hs rows
    unsigned short* stag = Hs + rbase * 136;
    int node = row0 + rbase + ln;
    bool wr = node < M;

    bf16x8 a_cur[4], a_nxt[4];
#pragma unroll
    for (int ks = 0; ks < 4; ++ks)
        a_cur[ks] = *(const bf16x8*)(Apack + ((size_t)(ks * 4 + kq) * 512 + ln) * 8);

#pragma unroll
    for (int pass = 0; pass < 4; ++pass) {
        int colp = pass * 128;
#pragma unroll
        for (int mt = 0; mt < 8; ++mt) {
            // prefetch next fragment (next mt, or next pass's mt=0)
            int nidx = pass * 8 + mt + 1;
            if (nidx < 32) {
                int ncol = (nidx >> 3) * 128 + (nidx & 7) * 16 + ln;
#pragma unroll
                for (int ks = 0; ks < 4; ++ks)
                    a_nxt[ks] = *(const bf16x8*)(Apack + ((size_t)(ks * 4 + kq) * 512 + ncol) * 8);
            }

            f32x4 acc = {0.f, 0.f, 0.f, 0.f};
#pragma unroll
            for (int ks = 0; ks < 4; ++ks)
                acc = __builtin_amdgcn_mfma_f32_16x16x32_bf16(a_cur[ks], bfr[ks], acc, 0, 0, 0);

            int col = colp + mt * 16 + kq * 4;
            float4 bb = *(const float4*)(bproj + col);
            ushort4 o;
            o.x = f2bfu(acc[0] + bb.x);
            o.y = f2bfu(acc[1] + bb.y);
            o.z = f2bfu(acc[2] + bb.z);
            o.w = f2bfu(acc[3] + bb.w);
            *(ushort4*)&stag[ln * 136 + mt * 16 + kq * 4] = o;

#pragma unroll
            for (int ks = 0; ks < 4; ++ks)
                a_cur[ks] = a_nxt[ks];
        }
        // 16 rows x 128 cols -> full 64B-line stores
#pragma unroll
        for (int i = 0; i < 4; ++i) {
            uint4 v = *(const uint4*)&stag[ln * 136 + i * 32 + kq * 8];
            if (wr)
                *(uint4*)(out + (size_t)node * 512 + colp + i * 32 + kq * 8) = v;
        }
    }
}

// ---------------------------------------------------------------------------
// final GEMM (MFMA): C[M,128] = relu(A[M,128] @ Wp + bp), in place (A == C)
// ---------------------------------------------------------------------------
__global__ __launch_bounds__(256) void final_gemm_kernel(
    const float* __restrict__ A, const bf16_t* __restrict__ Ppack,
    const float* __restrict__ bp, float* __restrict__ C, int M)
{
    __shared__ unsigned short Hs[64 * 136];
    int t = threadIdx.x;
    int lane = t & 63;
    int w = t >> 6;
    int row0 = blockIdx.x * 64;

#pragma unroll
    for (int i = 0; i < 8; ++i) {
        int f4 = i * 256 + t;
        int r = f4 >> 5;
        int c4 = (f4 & 31) * 4;
        float4 v = make_float4(0.f, 0.f, 0.f, 0.f);
        if (row0 + r < M)
            v = ((const float4*)(A + (size_t)(row0 + r) * 128))[f4 & 31];
        ushort4 o;
        o.x = f2bfu(v.x); o.y = f2bfu(v.y); o.z = f2bfu(v.z); o.w = f2bfu(v.w);
        *(ushort4*)&Hs[r * 136 + c4] = o;
    }
    __syncthreads();

    int kq = lane >> 4;
    int ln = lane & 15;

    f32x4 acc[2][4];
#pragma unroll
    for (int mt = 0; mt < 2; ++mt)
#pragma unroll
        for (int nt = 0; nt < 4; ++nt) {
            f32x4 z = {0.f, 0.f, 0.f, 0.f};
            acc[mt][nt] = z;
        }

#pragma unroll
    for (int ks = 0; ks < 4; ++ks) {
        bf16x8 bfr[4];
#pragma unroll
        for (int nt = 0; nt < 4; ++nt) {
            const uint4* p = (const uint4*)&Hs[(nt * 16 + ln) * 136 + ks * 32 + kq * 8];
            bfr[nt] = __builtin_bit_cast(bf16x8, *p);
        }
        bf16x8 afr[2];
#pragma unroll
        for (int mt = 0; mt < 2; ++mt) {
            int colA = w * 32 + mt * 16 + ln;
            afr[mt] = *(const bf16x8*)(Ppack + ((size_t)(ks * 4 + kq) * 128 + colA) * 8);
        }
#pragma unroll
        for (int mt = 0; mt < 2; ++mt)
#pragma unroll
            for (int nt = 0; nt < 4; ++nt)
                acc[mt][nt] = __builtin_amdgcn_mfma_f32_16x16x32_bf16(
                    afr[mt], bfr[nt], acc[mt][nt], 0, 0, 0);
    }

#pragma unroll
    for (int mt = 0; mt < 2; ++mt) {
        int col = w * 32 + mt * 16 + kq * 4;
        float4 bb = *(const float4*)(bp + col);
#pragma unroll
        for (int nt = 0; nt < 4; ++nt) {
            int node = row0 + nt * 16 + ln;
            if (node < M) {
                float4 o;
                o.x = fmaxf(acc[mt][nt][0] + bb.x, 0.f);
                o.y = fmaxf(acc[mt][nt][1] + bb.y, 0.f);
                o.z = fmaxf(acc[mt][nt][2] + bb.z, 0.f);
                o.w = fmaxf(acc[mt][nt][3] + bb.w, 0.f);
                *(float4*)(C + (size_t)node * 128 + col) = o;
            }
        }
    }
}

// ---------------------------------------------------------------------------
// FUSED score + segment-softmax + aggregate (online softmax, no atomics).
// ---------------------------------------------------------------------------
__global__ __launch_bounds__(256) void softagg_kernel(
    const unsigned short* __restrict__ fs, const unsigned short* __restrict__ fdp,
    const float* __restrict__ attn, const int* __restrict__ src,
    const int* __restrict__ offs, const int* __restrict__ deg,
    const int* __restrict__ eidx, float* __restrict__ out)
{
    int d = blockIdx.x * 4 + (threadIdx.x >> 6);
    if (d >= NE_N) return;
    int l = threadIdx.x & 63;
    int r0 = offs[d];
    int n = deg[d];
    int o = l * 8;

    uint4 fv = *(const uint4*)(fdp + (size_t)d * 512 + o);
    float fdv[8] = { blo(fv.x), bhi(fv.x), blo(fv.y), bhi(fv.y),
                     blo(fv.z), bhi(fv.z), blo(fv.w), bhi(fv.w) };
    float4 w0 = *(const float4*)(attn + o);
    float4 w1 = *(const float4*)(attn + o + 4);
    float wv[8] = { w0.x, w0.y, w0.z, w0.w, w1.x, w1.y, w1.z, w1.w };

    float m = -1e30f, sm = 0.f;
    float acc[8];
#pragma unroll
    for (int j = 0; j < 8; ++j) acc[j] = 0.f;

    for (int base = 0; base < n; base += 64) {
        int cnt = min(n - base, 64);
        int sl = 0;
        if (l < cnt) sl = src[eidx[r0 + base + l]];
        for (int i = 0; i < cnt; ++i) {
            int s = __shfl(sl, i, 64);
            uint4 a = *(const uint4*)(fs + (size_t)s * 512 + o);
            float fsv[8] = { blo(a.x), bhi(a.x), blo(a.y), bhi(a.y),
                             blo(a.z), bhi(a.z), blo(a.w), bhi(a.w) };
            float p = 0.f;
#pragma unroll
            for (int j = 0; j < 8; ++j)
                p = fmaf(lrelu(fsv[j] + fdv[j]), wv[j], p);
#pragma unroll
            for (int mk = 1; mk < 16; mk <<= 1)
                p += __shfl_xor(p, mk, 64);
            float mn = fmaxf(m, p);
            float c  = __expf(m - mn);
            float av = __expf(p - mn);
            sm = sm * c + av;
            m = mn;
#pragma unroll
            for (int j = 0; j < 8; ++j)
                acc[j] = fmaf(av, fsv[j], acc[j] * c);
        }
    }

    float inv = (n > 0) ? 0.25f / sm : 0.f;
#pragma unroll
    for (int j = 0; j < 8; ++j) {
        float v = acc[j] * inv;
        v += __shfl_xor(v, 16, 64);
        v += __shfl_xor(v, 32, 64);
        acc[j] = v;
    }
    if (l < 16) {
        float4 o0 = make_float4(acc[0], acc[1], acc[2], acc[3]);
        float4 o1 = make_float4(acc[4], acc[5], acc[6], acc[7]);
        *(float4*)(out + (size_t)d * 128 + l * 8) = o0;
        *(float4*)(out + (size_t)d * 128 + l * 8 + 4) = o1;
    }
}

// ---------------------------------------------------------------------------
extern "C" void kernel_launch(void* const* d_in, const int* in_sizes, int n_in,
                              void* d_out, int out_size, void* d_ws, size_t ws_size,
                              hipStream_t stream)
{
    const float* v_feat = (const float*)d_in[0];
    const float* e_feat = (const float*)d_in[1];
    const float* Wv     = (const float*)d_in[2];
    const float* bv     = (const float*)d_in[3];
    const float* gv     = (const float*)d_in[4];
    const float* betav  = (const float*)d_in[5];
    const float* We     = (const float*)d_in[6];
    const float* be     = (const float*)d_in[7];
    const float* ge     = (const float*)d_in[8];
    const float* betae  = (const float*)d_in[9];
    const float* Wsrc   = (const float*)d_in[10];
    const float* bsrc   = (const float*)d_in[11];
    const float* Wdst   = (const float*)d_in[12];
    const float* bdst   = (const float*)d_in[13];
    const float* attn   = (const float*)d_in[14];
    const float* Wp     = (const float*)d_in[15];
    const float* bp     = (const float*)d_in[16];
    const int*   src    = (const int*)d_in[17];
    const int*   dst    = (const int*)d_in[18];
    float* out = (float*)d_out;

    unsigned short* fs = (unsigned short*)d_ws;
    unsigned short* fd = fs + (size_t)NV * 512;
    int* deg    = (int*)(fd + (size_t)NE_N * 512);
    int* offs   = deg + NE_N;
    int* cursor = offs + NE_N;
    int* bsum   = cursor + NE_N;
    int* eidx   = bsum + 512;
    bf16_t* pS  = (bf16_t*)(eidx + NEDGE);
    bf16_t* pD  = pS + 65536;
    bf16_t* pP  = pD + 65536;

    const int NB_SCAN = (NE_N + 255) / 256;   // 391

    prep_kernel<<<72, 256, 0, stream>>>(Wsrc, Wdst, Wp, pS, pD, pP);

    // CSR build
    hipMemsetAsync(deg, 0, (size_t)NE_N * sizeof(int), stream);
    count_kernel<<<(NEDGE + 255) / 256, 256, 0, stream>>>(dst, deg);
    scan1_kernel<<<NB_SCAN, 256, 0, stream>>>(deg, offs, bsum);
    scan2_kernel<<<1, 512, 0, stream>>>(bsum, NB_SCAN);
    scan3_kernel<<<NB_SCAN, 256, 0, stream>>>(offs, bsum, cursor);
    scatter_kernel<<<(NEDGE + 255) / 256, 256, 0, stream>>>(dst, cursor, eidx);

    enc_proj_kernel<<<3126, 256, 0, stream>>>(
        v_feat, Wv, bv, gv, betav, pS, bsrc, fs,
        e_feat, We, be, ge, betae, pD, bdst, fd,
        1563, 100000);

    softagg_kernel<<<NE_N / 4, 256, 0, stream>>>(fs, fd, attn, src, offs, deg,
                                                 eidx, out);

    final_gemm_kernel<<<1563, 256, 0, stream>>>(out, pP, bp, out, NE_N);
}